// Round 1
// baseline (584.336 us; speedup 1.0000x reference)
//
#include <hip/hip_runtime.h>
#include <hip/hip_bf16.h>

// Problem constants
#define BB 2
#define C1 256
#define C2 256
#define HH 64
#define WW 64
#define HW (HH * WW)     // 4096
#define K2 9
#define OCH 27           // offset-conv output channels
#define EPSV 1e-5f

// ---------------------------------------------------------------------------
// Kernel 1: offset conv. om[b][oc][h][w] = b_off[oc] + sum_{ic,kh,kw} ...
// One thread per output element (221184 total).
// ---------------------------------------------------------------------------
__global__ __launch_bounds__(256) void offset_conv_kernel(
    const float* __restrict__ x, const float* __restrict__ w_off,
    const float* __restrict__ b_off, float* __restrict__ om)
{
    int t = blockIdx.x * 256 + threadIdx.x;   // ((b*27+oc)*64+h)*64+w
    int w = t & 63;
    int h = (t >> 6) & 63;
    int oc = (t >> 12) % OCH;
    int b = t / (OCH * HW);

    const float* xb = x + b * C1 * HW;
    const float* wo = w_off + oc * C1 * 9;
    float acc = b_off[oc];

    for (int ic = 0; ic < C1; ic++) {
        const float* xc = xb + ic * HW;
        const float* wi = wo + ic * 9;
        #pragma unroll
        for (int kh = 0; kh < 3; kh++) {
            int yy = h - 1 + kh;
            if (yy < 0 || yy > 63) continue;
            #pragma unroll
            for (int kw = 0; kw < 3; kw++) {
                int xx = w - 1 + kw;
                if (xx < 0 || xx > 63) continue;
                acc += xc[yy * 64 + xx] * wi[kh * 3 + kw];
            }
        }
    }
    om[t] = acc;
}

// ---------------------------------------------------------------------------
// Kernel 2: deformable gather + GEMM + BN + SiLU.
// Block: 256 threads = 256 output channels; PIX=16 consecutive pixels.
// Phase 0: per (pixel,tap) compute 4 corner indices + (bilinear*mask) weights.
// K-loop: stage vals[CB][9][PIX] in LDS, accumulate acc[PIX] per thread.
// ---------------------------------------------------------------------------
#define PIX 16
#define CB 8

__global__ __launch_bounds__(256) void dcn_main_kernel(
    const float* __restrict__ x, const float* __restrict__ om,
    const float* __restrict__ w_dcn, const float* __restrict__ gamma,
    const float* __restrict__ beta, const float* __restrict__ rmean,
    const float* __restrict__ rvar, float* __restrict__ out)
{
    __shared__ int   sIdx[PIX][K2][4];
    __shared__ float sWt[PIX][K2][4];
    __shared__ float sVals[CB][K2][PIX];

    const int tid = threadIdx.x;
    const int pixBase = blockIdx.x * PIX;       // [0, 8192)
    const int b = pixBase >> 12;                // / 4096 (tile never crosses b)
    const int hwBase = pixBase & 4095;

    // Phase 0: bilinear metadata for 16 pixels x 9 taps (144 threads active)
    if (tid < PIX * K2) {
        int p = tid / K2, k = tid % K2;
        int hw = hwBase + p;
        int h = hw >> 6, w = hw & 63;
        const float* omb = om + b * OCH * HW;
        float dy = omb[(2 * k) * HW + hw];
        float dx = omb[(2 * k + 1) * HW + hw];
        float mm = omb[(18 + k) * HW + hw];
        mm = 1.0f / (1.0f + __expf(-mm));       // sigmoid(mask)
        float py = (float)(h - 1 + k / 3) + dy;
        float px = (float)(w - 1 + k % 3) + dx;
        float y0f = floorf(py), x0f = floorf(px);
        float ly = py - y0f, lx = px - x0f;
        int y0 = (int)y0f, x0 = (int)x0f;
        #pragma unroll
        for (int j = 0; j < 4; j++) {
            int yi = y0 + (j >> 1);
            int xi = x0 + (j & 1);
            bool valid = (yi >= 0) && (yi < HH) && (xi >= 0) && (xi < WW);
            int yc = min(max(yi, 0), HH - 1);
            int xc = min(max(xi, 0), WW - 1);
            sIdx[p][k][j] = yc * WW + xc;
            float wy = (j >> 1) ? ly : (1.0f - ly);
            float wx = (j & 1) ? lx : (1.0f - lx);
            sWt[p][k][j] = valid ? (wy * wx * mm) : 0.0f;
        }
    }
    __syncthreads();

    float acc[PIX];
    #pragma unroll
    for (int p = 0; p < PIX; p++) acc[p] = 0.0f;

    const float* xb = x + b * C1 * HW;
    const int o = tid;

    for (int cb = 0; cb < C1; cb += CB) {
        // Cooperative gather: CB*9*16 = 1152 values, 256 threads
        for (int v = tid; v < CB * K2 * PIX; v += 256) {
            int ci = v / (K2 * PIX);
            int rem = v % (K2 * PIX);
            int k = rem / PIX, p = rem % PIX;
            const float* xc = xb + (cb + ci) * HW;
            float s = 0.0f;
            #pragma unroll
            for (int j = 0; j < 4; j++)
                s += sWt[p][k][j] * xc[sIdx[p][k][j]];
            sVals[ci][k][p] = s;
        }
        __syncthreads();

        // Accumulate: thread o, weights w_dcn[o][cb+ci][k]; LDS reads are
        // wave-uniform addresses -> broadcast, conflict-free.
        const float* wp = w_dcn + o * (C1 * K2) + cb * K2;
        #pragma unroll
        for (int ci = 0; ci < CB; ci++) {
            #pragma unroll
            for (int k = 0; k < K2; k++) {
                float wv = wp[ci * K2 + k];
                const float4* vp = (const float4*)&sVals[ci][k][0];
                #pragma unroll
                for (int q = 0; q < 4; q++) {
                    float4 v4 = vp[q];
                    acc[4 * q + 0] += v4.x * wv;
                    acc[4 * q + 1] += v4.y * wv;
                    acc[4 * q + 2] += v4.z * wv;
                    acc[4 * q + 3] += v4.w * wv;
                }
            }
        }
        __syncthreads();
    }

    // Epilogue: BN (running stats) + SiLU. Each thread writes 16 consecutive
    // floats (one 64B line).
    float inv = gamma[o] * rsqrtf(rvar[o] + EPSV);
    float sh = beta[o] - rmean[o] * inv;
    float* op = out + (b * C2 + o) * HW + hwBase;
    #pragma unroll
    for (int p = 0; p < PIX; p++) {
        float y = acc[p] * inv + sh;
        op[p] = y / (1.0f + __expf(-y));
    }
}

// ---------------------------------------------------------------------------
extern "C" void kernel_launch(void* const* d_in, const int* in_sizes, int n_in,
                              void* d_out, int out_size, void* d_ws, size_t ws_size,
                              hipStream_t stream) {
    const float* x      = (const float*)d_in[0];
    const float* w_off  = (const float*)d_in[1];
    const float* b_off  = (const float*)d_in[2];
    const float* w_dcn  = (const float*)d_in[3];
    const float* gamma  = (const float*)d_in[4];
    const float* beta   = (const float*)d_in[5];
    const float* rmean  = (const float*)d_in[6];
    const float* rvar   = (const float*)d_in[7];
    float* out = (float*)d_out;

    float* om = (float*)d_ws;   // B*27*H*W floats = 884736 bytes

    int n_om = BB * OCH * HW;   // 221184
    offset_conv_kernel<<<n_om / 256, 256, 0, stream>>>(x, w_off, b_off, om);

    int n_blocks = BB * HW / PIX;   // 512
    dcn_main_kernel<<<n_blocks, 256, 0, stream>>>(x, om, w_dcn, gamma, beta,
                                                  rmean, rvar, out);
}

// Round 2
// 386.195 us; speedup vs baseline: 1.5131x; 1.5131x over previous
//
#include <hip/hip_runtime.h>
#include <hip/hip_bf16.h>

// Problem constants
#define BB 2
#define C1 256
#define C2 256
#define HH 64
#define WW 64
#define HW (HH * WW)     // 4096
#define K2 9
#define OCH 27           // offset-conv output channels
#define EPSV 1e-5f

// ---------------------------------------------------------------------------
// Kernel 0: init om with bias (offset conv accumulates atomically into it).
// ---------------------------------------------------------------------------
__global__ __launch_bounds__(256) void om_init_kernel(
    const float* __restrict__ b_off, float* __restrict__ om)
{
    int t = blockIdx.x * 256 + threadIdx.x;   // ((b*27+oc)*64+h)*64+w
    int oc = (t >> 12) % OCH;
    om[t] = b_off[oc];
}

// ---------------------------------------------------------------------------
// Kernel 1: offset conv, LDS-tiled.
// Block = 16x16 pixel tile, 32-ic chunk (IC_SPLIT=8). 256 blocks total.
// Stage 18x18x32 halo patch in LDS once; weights via uniform (scalar) loads;
// inner loop is pure v_fmac with SGPR weight operands. Partials combined
// with global fp32 atomicAdd.
// ---------------------------------------------------------------------------
#define ICB 32           // ics per block
#define IC_SPLIT (C1 / ICB)

__global__ __launch_bounds__(256) void offset_conv_kernel(
    const float* __restrict__ x, const float* __restrict__ w_off,
    float* __restrict__ om)
{
    __shared__ float patch[ICB][18 * 18];

    const int tid = threadIdx.x;
    const int icc  = blockIdx.x % IC_SPLIT;
    const int tile = blockIdx.x / IC_SPLIT;      // [0, 32)
    const int b  = tile >> 4;
    const int t16 = tile & 15;
    const int h0 = (t16 >> 2) * 16;
    const int w0 = (t16 & 3) * 16;

    // Stage halo patch: 32 ics x 18x18, zero-padded at image borders.
    const float* xb = x + (b * C1 + icc * ICB) * HW;
    for (int i = tid; i < ICB * 324; i += 256) {
        int ic = i / 324;
        int rem = i - ic * 324;
        int r = rem / 18;
        int c = rem - r * 18;
        int hh = h0 - 1 + r;
        int ww = w0 - 1 + c;
        float v = 0.0f;
        if (hh >= 0 && hh < HH && ww >= 0 && ww < WW)
            v = xb[ic * HW + hh * WW + ww];
        patch[ic][rem] = v;
    }
    __syncthreads();

    const int r = tid >> 4;
    const int c = tid & 15;

    float acc[OCH];
    #pragma unroll
    for (int oc = 0; oc < OCH; oc++) acc[oc] = 0.0f;

    for (int ic = 0; ic < ICB; ic++) {
        float nb[9];
        #pragma unroll
        for (int dr = 0; dr < 3; dr++)
            #pragma unroll
            for (int dc = 0; dc < 3; dc++)
                nb[dr * 3 + dc] = patch[ic][(r + dr) * 18 + (c + dc)];

        // w_off[oc][icc*ICB+ic][k] — all-uniform addresses -> scalar loads
        const float* wbase = w_off + (icc * ICB + ic) * 9;
        #pragma unroll
        for (int oc = 0; oc < OCH; oc++) {
            const float* wp = wbase + oc * (C1 * 9);
            #pragma unroll
            for (int k = 0; k < 9; k++)
                acc[oc] += nb[k] * wp[k];
        }
    }

    const int hw = (h0 + r) * WW + (w0 + c);
    float* ob = om + b * OCH * HW + hw;
    #pragma unroll
    for (int oc = 0; oc < OCH; oc++)
        atomicAdd(ob + oc * HW, acc[oc]);
}

// ---------------------------------------------------------------------------
// Kernel 2: deformable gather + GEMM + BN + SiLU. (unchanged this round)
// ---------------------------------------------------------------------------
#define PIX 16
#define CB 8

__global__ __launch_bounds__(256) void dcn_main_kernel(
    const float* __restrict__ x, const float* __restrict__ om,
    const float* __restrict__ w_dcn, const float* __restrict__ gamma,
    const float* __restrict__ beta, const float* __restrict__ rmean,
    const float* __restrict__ rvar, float* __restrict__ out)
{
    __shared__ int   sIdx[PIX][K2][4];
    __shared__ float sWt[PIX][K2][4];
    __shared__ float sVals[CB][K2][PIX];

    const int tid = threadIdx.x;
    const int pixBase = blockIdx.x * PIX;       // [0, 8192)
    const int b = pixBase >> 12;
    const int hwBase = pixBase & 4095;

    if (tid < PIX * K2) {
        int p = tid / K2, k = tid % K2;
        int hw = hwBase + p;
        int h = hw >> 6, w = hw & 63;
        const float* omb = om + b * OCH * HW;
        float dy = omb[(2 * k) * HW + hw];
        float dx = omb[(2 * k + 1) * HW + hw];
        float mm = omb[(18 + k) * HW + hw];
        mm = 1.0f / (1.0f + __expf(-mm));
        float py = (float)(h - 1 + k / 3) + dy;
        float px = (float)(w - 1 + k % 3) + dx;
        float y0f = floorf(py), x0f = floorf(px);
        float ly = py - y0f, lx = px - x0f;
        int y0 = (int)y0f, x0 = (int)x0f;
        #pragma unroll
        for (int j = 0; j < 4; j++) {
            int yi = y0 + (j >> 1);
            int xi = x0 + (j & 1);
            bool valid = (yi >= 0) && (yi < HH) && (xi >= 0) && (xi < WW);
            int yc = min(max(yi, 0), HH - 1);
            int xc = min(max(xi, 0), WW - 1);
            sIdx[p][k][j] = yc * WW + xc;
            float wy = (j >> 1) ? ly : (1.0f - ly);
            float wx = (j & 1) ? lx : (1.0f - lx);
            sWt[p][k][j] = valid ? (wy * wx * mm) : 0.0f;
        }
    }
    __syncthreads();

    float acc[PIX];
    #pragma unroll
    for (int p = 0; p < PIX; p++) acc[p] = 0.0f;

    const float* xb = x + b * C1 * HW;
    const int o = tid;

    for (int cb = 0; cb < C1; cb += CB) {
        for (int v = tid; v < CB * K2 * PIX; v += 256) {
            int ci = v / (K2 * PIX);
            int rem = v % (K2 * PIX);
            int k = rem / PIX, p = rem % PIX;
            const float* xc = xb + (cb + ci) * HW;
            float s = 0.0f;
            #pragma unroll
            for (int j = 0; j < 4; j++)
                s += sWt[p][k][j] * xc[sIdx[p][k][j]];
            sVals[ci][k][p] = s;
        }
        __syncthreads();

        const float* wp = w_dcn + o * (C1 * K2) + cb * K2;
        #pragma unroll
        for (int ci = 0; ci < CB; ci++) {
            #pragma unroll
            for (int k = 0; k < K2; k++) {
                float wv = wp[ci * K2 + k];
                const float4* vp = (const float4*)&sVals[ci][k][0];
                #pragma unroll
                for (int q = 0; q < 4; q++) {
                    float4 v4 = vp[q];
                    acc[4 * q + 0] += v4.x * wv;
                    acc[4 * q + 1] += v4.y * wv;
                    acc[4 * q + 2] += v4.z * wv;
                    acc[4 * q + 3] += v4.w * wv;
                }
            }
        }
        __syncthreads();
    }

    float inv = gamma[o] * rsqrtf(rvar[o] + EPSV);
    float sh = beta[o] - rmean[o] * inv;
    float* op = out + (b * C2 + o) * HW + hwBase;
    #pragma unroll
    for (int p = 0; p < PIX; p++) {
        float y = acc[p] * inv + sh;
        op[p] = y / (1.0f + __expf(-y));
    }
}

// ---------------------------------------------------------------------------
extern "C" void kernel_launch(void* const* d_in, const int* in_sizes, int n_in,
                              void* d_out, int out_size, void* d_ws, size_t ws_size,
                              hipStream_t stream) {
    const float* x      = (const float*)d_in[0];
    const float* w_off  = (const float*)d_in[1];
    const float* b_off  = (const float*)d_in[2];
    const float* w_dcn  = (const float*)d_in[3];
    const float* gamma  = (const float*)d_in[4];
    const float* beta   = (const float*)d_in[5];
    const float* rmean  = (const float*)d_in[6];
    const float* rvar   = (const float*)d_in[7];
    float* out = (float*)d_out;

    float* om = (float*)d_ws;   // B*27*H*W floats = 884736 bytes

    int n_om = BB * OCH * HW;   // 221184
    om_init_kernel<<<n_om / 256, 256, 0, stream>>>(b_off, om);

    int n_conv_blocks = BB * 16 * IC_SPLIT;   // 256
    offset_conv_kernel<<<n_conv_blocks, 256, 0, stream>>>(x, w_off, om);

    int n_blocks = BB * HW / PIX;   // 512
    dcn_main_kernel<<<n_blocks, 256, 0, stream>>>(x, om, w_dcn, gamma, beta,
                                                  rmean, rvar, out);
}

// Round 3
// 217.628 us; speedup vs baseline: 2.6850x; 1.7746x over previous
//
#include <hip/hip_runtime.h>
#include <hip/hip_bf16.h>
#include <math.h>

typedef __bf16 bf16x8 __attribute__((ext_vector_type(8)));
typedef float  f32x4  __attribute__((ext_vector_type(4)));

#define BB 2
#define C1 256
#define C2 256
#define HH 64
#define WW 64
#define HW 4096
#define K2 9
#define OCH 27
#define KK 2304          // C1*K2
#define EPSV 1e-5f

// workspace layout (bytes)
#define OM_OFF   0u          // 221184 f32  = 884736 B
#define PART_OFF 884736u     // 16*221184 f32 = 14155776 B
#define WBF_OFF  15040512u   // 589824 bf16 = 1179648 B
#define VALS_OFF 16220160u   // 8192*2304 bf16 = 37748736 B  (total ~51.5 MB)

// ---------------------------------------------------------------------------
// Kernel A: convert w_dcn fp32 [256][2304] -> bf16 (same layout = B^T, K-major)
// ---------------------------------------------------------------------------
struct B4 { __bf16 a, b, c, d; };   // 8 bytes

__global__ __launch_bounds__(256) void wprep_kernel(
    const float* __restrict__ w, __bf16* __restrict__ wbf)
{
    int i = (blockIdx.x * 256 + threadIdx.x) * 4;   // 576 blocks * 1024 = 589824
    float4 f = *(const float4*)(w + i);
    B4 o = { (__bf16)f.x, (__bf16)f.y, (__bf16)f.z, (__bf16)f.w };
    *(B4*)(wbf + i) = o;
}

// ---------------------------------------------------------------------------
// Kernel B: offset conv partials. 512 blocks = 2(b) x 16(tile) x 16(ic-split).
// Patch + weights staged in LDS; no scalar-load latency chain; partials to ws.
// ---------------------------------------------------------------------------
#define ICB 16

__global__ __launch_bounds__(256) void offset_partial_kernel(
    const float* __restrict__ x, const float* __restrict__ w_off,
    float* __restrict__ partials)
{
    __shared__ float  patch[ICB][324];        // 20736 B
    __shared__ float4 wts4[ICB * OCH * 3];    // 20736 B (9 used of 12, padded)

    const int tid  = threadIdx.x;
    const int icc  = blockIdx.x & 15;
    const int tile = blockIdx.x >> 4;         // [0,32)
    const int b    = tile >> 4;
    const int t16  = tile & 15;
    const int h0   = (t16 >> 2) * 16;
    const int w0   = (t16 & 3) * 16;

    const float* xb = x + (b * C1 + icc * ICB) * HW;
    for (int i = tid; i < ICB * 324; i += 256) {
        int ic = i / 324, rem = i - ic * 324;
        int r = rem / 18, c = rem - r * 18;
        int hh = h0 - 1 + r, ww = w0 - 1 + c;
        float v = 0.f;
        if (hh >= 0 && hh < HH && ww >= 0 && ww < WW)
            v = xb[ic * HW + hh * WW + ww];
        patch[ic][rem] = v;
    }
    float* wf = (float*)wts4;
    for (int j = tid; j < ICB * OCH * 9; j += 256) {
        int k = j % 9, t2 = j / 9;
        int oc = t2 % OCH, ic = t2 / OCH;
        wf[(ic * OCH + oc) * 12 + k] = w_off[(oc * C1 + icc * ICB + ic) * 9 + k];
    }
    __syncthreads();

    const int r = tid >> 4, c = tid & 15;
    float acc[OCH];
    #pragma unroll
    for (int oc = 0; oc < OCH; oc++) acc[oc] = 0.f;

    for (int ic = 0; ic < ICB; ic++) {
        float nb[9];
        #pragma unroll
        for (int dr = 0; dr < 3; dr++)
            #pragma unroll
            for (int dc = 0; dc < 3; dc++)
                nb[dr * 3 + dc] = patch[ic][(r + dr) * 18 + (c + dc)];
        const float4* wp = wts4 + ic * OCH * 3;
        #pragma unroll
        for (int oc = 0; oc < OCH; oc++) {
            float4 wa = wp[oc * 3 + 0];
            float4 wb = wp[oc * 3 + 1];
            float4 wc = wp[oc * 3 + 2];
            acc[oc] += nb[0] * wa.x + nb[1] * wa.y + nb[2] * wa.z + nb[3] * wa.w
                     + nb[4] * wb.x + nb[5] * wb.y + nb[6] * wb.z + nb[7] * wb.w
                     + nb[8] * wc.x;
        }
    }

    const int hw = (h0 + r) * WW + (w0 + c);
    float* pb = partials + (size_t)icc * 221184 + (b * OCH) * HW + hw;
    #pragma unroll
    for (int oc = 0; oc < OCH; oc++) pb[oc * HW] = acc[oc];
}

// ---------------------------------------------------------------------------
// Kernel C: reduce 16 partials + bias -> om
// ---------------------------------------------------------------------------
__global__ __launch_bounds__(256) void offset_reduce_kernel(
    const float* __restrict__ partials, const float* __restrict__ b_off,
    float* __restrict__ om)
{
    int t = blockIdx.x * 256 + threadIdx.x;   // < 221184
    int oc = (t >> 12) % OCH;
    float s = b_off[oc];
    #pragma unroll
    for (int i = 0; i < 16; i++) s += partials[i * 221184 + t];
    om[t] = s;
}

// ---------------------------------------------------------------------------
// Kernel D: deformable gather -> vals bf16 [8192 pixels][2304 (c*9+k)].
// Block = 64-pixel image row x 32 channels (grid 1024). Lanes = pixels so
// corner loads coalesce; output transposed via skewed LDS tile (stride 146
// bf16 = 73 dwords, odd -> conflict-free) then written coalesced.
// ---------------------------------------------------------------------------
__global__ __launch_bounds__(256) void gather_kernel(
    const float* __restrict__ x, const float* __restrict__ om,
    __bf16* __restrict__ vals)
{
    __shared__ int    sIdx[9][4][64];      // 9216 B
    __shared__ float  sWt[9][4][64];       // 9216 B
    __shared__ __bf16 tile[64][146];       // 18688 B

    const int tid = threadIdx.x;
    const int rg = blockIdx.x >> 3;        // 128 row-groups
    const int ch = blockIdx.x & 7;         // 8 channel slices of 32
    const int pixBase = rg * 64;
    const int b = pixBase >> 12;
    const int hwBase = pixBase & 4095;
    const int h = hwBase >> 6;             // row-aligned: w == p

    for (int t = tid; t < 576; t += 256) {
        int k = t >> 6, p = t & 63;
        int hw = hwBase + p;
        const float* omb = om + (size_t)b * OCH * HW;
        float dy  = omb[(2 * k) * HW + hw];
        float dx  = omb[(2 * k + 1) * HW + hw];
        float mmv = omb[(18 + k) * HW + hw];
        mmv = 1.f / (1.f + __expf(-mmv));
        float py = (float)(h - 1 + k / 3) + dy;
        float px = (float)(p - 1 + k % 3) + dx;
        float y0f = floorf(py), x0f = floorf(px);
        float ly = py - y0f, lx = px - x0f;
        int y0 = (int)y0f, x0 = (int)x0f;
        #pragma unroll
        for (int j = 0; j < 4; j++) {
            int yi = y0 + (j >> 1), xi = x0 + (j & 1);
            bool valid = (yi >= 0) && (yi < HH) && (xi >= 0) && (xi < WW);
            int yc = min(max(yi, 0), HH - 1);
            int xc = min(max(xi, 0), WW - 1);
            sIdx[k][j][p] = yc * WW + xc;
            float wy = (j >> 1) ? ly : 1.f - ly;
            float wx = (j & 1) ? lx : 1.f - lx;
            sWt[k][j][p] = valid ? wy * wx * mmv : 0.f;
        }
    }
    __syncthreads();

    const int wv = tid >> 6, lane = tid & 63;
    const int p2 = tid >> 2, q2 = tid & 3;

    for (int chunk = 0; chunk < 2; chunk++) {
        for (int tsk = wv; tsk < 144; tsk += 4) {   // tsk = ci*9+k, uniform/wave
            int ci = tsk / 9;
            int k = tsk - ci * 9;
            const float* xc = x + (size_t)(b * C1 + ch * 32 + chunk * 16 + ci) * HW;
            float v = sWt[k][0][lane] * xc[sIdx[k][0][lane]]
                    + sWt[k][1][lane] * xc[sIdx[k][1][lane]]
                    + sWt[k][2][lane] * xc[sIdx[k][2][lane]]
                    + sWt[k][3][lane] * xc[sIdx[k][3][lane]];
            tile[lane][tsk] = (__bf16)v;
        }
        __syncthreads();
        {
            const unsigned* tr = (const unsigned*)&tile[p2][0];
            unsigned* gr = (unsigned*)vals + (size_t)(pixBase + p2) * 1152
                         + ch * 144 + chunk * 72;
            #pragma unroll
            for (int jj = 0; jj < 18; jj++)
                gr[q2 + jj * 4] = tr[q2 + jj * 4];
        }
        __syncthreads();
    }
}

// ---------------------------------------------------------------------------
// Kernel E: bf16 MFMA GEMM  out[pg][o] = vals[pg][:] . wbf[o][:]  + BN + SiLU.
// M-tile 32 x N 256, grid 256. m97 pattern: global_load_lds width-16 staging,
// 16x16x32 bf16 MFMA, wave w owns N-slice [w*64, w*64+64).
// ---------------------------------------------------------------------------
__global__ __launch_bounds__(256) void gemm_kernel(
    const __bf16* __restrict__ vals, const __bf16* __restrict__ wbf,
    const float* __restrict__ gamma, const float* __restrict__ beta,
    const float* __restrict__ rmean, const float* __restrict__ rvar,
    float* __restrict__ out)
{
    __shared__ __bf16 sA[32 * 64];    // 4 KB
    __shared__ __bf16 sB[256 * 64];   // 32 KB

    const int tid = threadIdx.x, wv = tid >> 6, lane = tid & 63;
    const int pixBase = blockIdx.x * 32;
    const int l3 = lane >> 3, l7 = lane & 7;
    const int n15 = lane & 15, q4 = lane >> 4;

    f32x4 acc[2][4];
    #pragma unroll
    for (int i = 0; i < 2; i++)
        #pragma unroll
        for (int j = 0; j < 4; j++)
            acc[i][j] = (f32x4){0.f, 0.f, 0.f, 0.f};

    const char* gA = (const char*)vals;
    const char* gB = (const char*)wbf;

    for (int kb = 0; kb < 36; kb++) {
        const int cbyte = kb * 128;   // 64 bf16 per chunk
        {   // A-tile: 32 rows x 128 B; wave w stages rows w*8..w*8+8
            const char* g = gA + (size_t)(pixBase + wv * 8 + l3) * 4608 + cbyte + l7 * 16;
            char* l = (char*)sA + wv * 1024;
            __builtin_amdgcn_global_load_lds(
                (const __attribute__((address_space(1))) void*)g,
                (__attribute__((address_space(3))) void*)l, 16, 0, 0);
        }
        #pragma unroll
        for (int j = 0; j < 8; j++) {   // B-tile: 256 rows x 128 B
            const char* g = gB + (size_t)(wv * 64 + j * 8 + l3) * 4608 + cbyte + l7 * 16;
            char* l = (char*)sB + wv * 8192 + j * 1024;
            __builtin_amdgcn_global_load_lds(
                (const __attribute__((address_space(1))) void*)g,
                (__attribute__((address_space(3))) void*)l, 16, 0, 0);
        }
        __syncthreads();

        bf16x8 af[2][2];
        #pragma unroll
        for (int mf = 0; mf < 2; mf++)
            #pragma unroll
            for (int ks = 0; ks < 2; ks++)
                af[mf][ks] = *(const bf16x8*)&sA[(mf * 16 + n15) * 64 + q4 * 8 + ks * 32];

        #pragma unroll
        for (int nf = 0; nf < 4; nf++) {
            #pragma unroll
            for (int ks = 0; ks < 2; ks++) {
                bf16x8 bfr = *(const bf16x8*)&sB[(wv * 64 + nf * 16 + n15) * 64 + q4 * 8 + ks * 32];
                #pragma unroll
                for (int mf = 0; mf < 2; mf++)
                    acc[mf][nf] = __builtin_amdgcn_mfma_f32_16x16x32_bf16(
                        af[mf][ks], bfr, acc[mf][nf], 0, 0, 0);
            }
        }
        __syncthreads();
    }

    // Epilogue: C/D layout col(lane&15)=o-within-frag, row(q4*4+r)=pixel
    #pragma unroll
    for (int nf = 0; nf < 4; nf++) {
        int o = wv * 64 + nf * 16 + n15;
        float inv = gamma[o] * rsqrtf(rvar[o] + EPSV);
        float sh = beta[o] - rmean[o] * inv;
        #pragma unroll
        for (int mf = 0; mf < 2; mf++) {
            #pragma unroll
            for (int r = 0; r < 4; r++) {
                int m = mf * 16 + q4 * 4 + r;
                int pg = pixBase + m;
                float y = acc[mf][nf][r] * inv + sh;
                out[(size_t)(((pg >> 12) * C2 + o) << 12) + (pg & 4095)]
                    = y * (1.f / (1.f + __expf(-y)));
            }
        }
    }
}

// ---------------------------------------------------------------------------
extern "C" void kernel_launch(void* const* d_in, const int* in_sizes, int n_in,
                              void* d_out, int out_size, void* d_ws, size_t ws_size,
                              hipStream_t stream) {
    const float* x      = (const float*)d_in[0];
    const float* w_off  = (const float*)d_in[1];
    const float* b_off  = (const float*)d_in[2];
    const float* w_dcn  = (const float*)d_in[3];
    const float* gamma  = (const float*)d_in[4];
    const float* beta   = (const float*)d_in[5];
    const float* rmean  = (const float*)d_in[6];
    const float* rvar   = (const float*)d_in[7];
    float* out = (float*)d_out;

    char* ws = (char*)d_ws;
    float*  om       = (float*)(ws + OM_OFF);
    float*  partials = (float*)(ws + PART_OFF);
    __bf16* wbf      = (__bf16*)(ws + WBF_OFF);
    __bf16* vals     = (__bf16*)(ws + VALS_OFF);

    wprep_kernel<<<576, 256, 0, stream>>>(w_dcn, wbf);
    offset_partial_kernel<<<512, 256, 0, stream>>>(x, w_off, partials);
    offset_reduce_kernel<<<864, 256, 0, stream>>>(partials, b_off, om);
    gather_kernel<<<1024, 256, 0, stream>>>(x, om, vals);
    gemm_kernel<<<256, 256, 0, stream>>>(vals, wbf, gamma, beta, rmean, rvar, out);
}

// Round 4
// 204.407 us; speedup vs baseline: 2.8587x; 1.0647x over previous
//
#include <hip/hip_runtime.h>
#include <hip/hip_bf16.h>
#include <math.h>

typedef __bf16 bf16x8 __attribute__((ext_vector_type(8)));
typedef float  f32x4  __attribute__((ext_vector_type(4)));

#define BB 2
#define C1 256
#define C2 256
#define HH 64
#define WW 64
#define HW 4096
#define K2 9
#define OCH 27
#define EPSV 1e-5f

// workspace layout (bytes)
#define OM_OFF   0u          // 221184 f32  = 884736 B
#define PART_OFF 884736u     // 16*221184 f32 = 14155776 B
#define WBF_OFF  15040512u   // 589824 bf16 = 1179648 B   (total ~16.2 MB)

// ---------------------------------------------------------------------------
// Kernel A: w_dcn fp32 [o][c*9+k] -> bf16 k-major [o][k*256+c].
// Write-coalesced (c fastest); reads stride-9 but tiny + L2-hot.
// ---------------------------------------------------------------------------
__global__ __launch_bounds__(256) void wprep_kernel(
    const float* __restrict__ w, __bf16* __restrict__ wbfT)
{
    int t = blockIdx.x * 256 + threadIdx.x;    // < 589824
    int o = t / 2304;
    int r = t - o * 2304;
    int k = r >> 8;                            // K-index = k*256+c
    int c = r & 255;
    wbfT[t] = (__bf16)w[o * 2304 + c * 9 + k];
}

// ---------------------------------------------------------------------------
// Kernel B: offset conv partials (unchanged from round 3).
// ---------------------------------------------------------------------------
#define ICB 16

__global__ __launch_bounds__(256) void offset_partial_kernel(
    const float* __restrict__ x, const float* __restrict__ w_off,
    float* __restrict__ partials)
{
    __shared__ float  patch[ICB][324];
    __shared__ float4 wts4[ICB * OCH * 3];

    const int tid  = threadIdx.x;
    const int icc  = blockIdx.x & 15;
    const int tile = blockIdx.x >> 4;
    const int b    = tile >> 4;
    const int t16  = tile & 15;
    const int h0   = (t16 >> 2) * 16;
    const int w0   = (t16 & 3) * 16;

    const float* xb = x + (b * C1 + icc * ICB) * HW;
    for (int i = tid; i < ICB * 324; i += 256) {
        int ic = i / 324, rem = i - ic * 324;
        int r = rem / 18, c = rem - r * 18;
        int hh = h0 - 1 + r, ww = w0 - 1 + c;
        float v = 0.f;
        if (hh >= 0 && hh < HH && ww >= 0 && ww < WW)
            v = xb[ic * HW + hh * WW + ww];
        patch[ic][rem] = v;
    }
    float* wf = (float*)wts4;
    for (int j = tid; j < ICB * OCH * 9; j += 256) {
        int k = j % 9, t2 = j / 9;
        int oc = t2 % OCH, ic = t2 / OCH;
        wf[(ic * OCH + oc) * 12 + k] = w_off[(oc * C1 + icc * ICB + ic) * 9 + k];
    }
    __syncthreads();

    const int r = tid >> 4, c = tid & 15;
    float acc[OCH];
    #pragma unroll
    for (int oc = 0; oc < OCH; oc++) acc[oc] = 0.f;

    for (int ic = 0; ic < ICB; ic++) {
        float nb[9];
        #pragma unroll
        for (int dr = 0; dr < 3; dr++)
            #pragma unroll
            for (int dc = 0; dc < 3; dc++)
                nb[dr * 3 + dc] = patch[ic][(r + dr) * 18 + (c + dc)];
        const float4* wp = wts4 + ic * OCH * 3;
        #pragma unroll
        for (int oc = 0; oc < OCH; oc++) {
            float4 wa = wp[oc * 3 + 0];
            float4 wb = wp[oc * 3 + 1];
            float4 wc = wp[oc * 3 + 2];
            acc[oc] += nb[0] * wa.x + nb[1] * wa.y + nb[2] * wa.z + nb[3] * wa.w
                     + nb[4] * wb.x + nb[5] * wb.y + nb[6] * wb.z + nb[7] * wb.w
                     + nb[8] * wc.x;
        }
    }

    const int hw = (h0 + r) * WW + (w0 + c);
    float* pb = partials + (size_t)icc * 221184 + (b * OCH) * HW + hw;
    #pragma unroll
    for (int oc = 0; oc < OCH; oc++) pb[oc * HW] = acc[oc];
}

// ---------------------------------------------------------------------------
// Kernel C: reduce 16 partials + bias -> om
// ---------------------------------------------------------------------------
__global__ __launch_bounds__(256) void offset_reduce_kernel(
    const float* __restrict__ partials, const float* __restrict__ b_off,
    float* __restrict__ om)
{
    int t = blockIdx.x * 256 + threadIdx.x;
    int oc = (t >> 12) % OCH;
    float s = b_off[oc];
    #pragma unroll
    for (int i = 0; i < 16; i++) s += partials[i * 221184 + t];
    om[t] = s;
}

// ---------------------------------------------------------------------------
// Kernel D: FUSED gather + MFMA GEMM + BN + SiLU.
// Block = 32 pixels (half image row) x all 256 output channels; grid 256.
// K order is k-major (K = k*256 + c): per tap k, the 4 corner idx/wt live in
// registers and are reused across all 256 channels. Gather goes straight to
// the LDS A-tile (no vals round-trip). B staged via global_load_lds width-16.
// ---------------------------------------------------------------------------
__global__ __launch_bounds__(256) void fused_kernel(
    const float* __restrict__ x, const float* __restrict__ om,
    const __bf16* __restrict__ wbfT,
    const float* __restrict__ gamma, const float* __restrict__ beta,
    const float* __restrict__ rmean, const float* __restrict__ rvar,
    float* __restrict__ out)
{
    __shared__ __bf16 sA[32 * 72];       // 4608 B, row stride 72 (pad vs 64)
    __shared__ __bf16 sB[256 * 64];      // 32 KB
    __shared__ int    sIdx[32][9][4];    // byte offsets into a channel plane
    __shared__ float  sWt[32][9][4];     // bilinear*mask weights

    const int tid  = threadIdx.x;
    const int wv   = tid >> 6;
    const int lane = tid & 63;
    const int pixBase = blockIdx.x * 32;
    const int b = pixBase >> 12;
    const int hwBase = pixBase & 4095;
    const int h  = hwBase >> 6;
    const int w0 = hwBase & 63;

    // --- Phase 0: bilinear metadata for 32 pixels x 9 taps ---
    for (int t = tid; t < 32 * 9; t += 256) {
        int p = t / 9, k = t - (t / 9) * 9;
        int hw = hwBase + p;
        const float* omb = om + (size_t)b * OCH * HW;
        float dy  = omb[(2 * k) * HW + hw];
        float dx  = omb[(2 * k + 1) * HW + hw];
        float mmv = omb[(18 + k) * HW + hw];
        mmv = 1.f / (1.f + __expf(-mmv));
        float py = (float)(h - 1 + k / 3) + dy;
        float px = (float)(w0 + p - 1 + k % 3) + dx;
        float y0f = floorf(py), x0f = floorf(px);
        float ly = py - y0f, lx = px - x0f;
        int y0 = (int)y0f, x0 = (int)x0f;
        #pragma unroll
        for (int j = 0; j < 4; j++) {
            int yi = y0 + (j >> 1), xi = x0 + (j & 1);
            bool valid = (yi >= 0) && (yi < HH) && (xi >= 0) && (xi < WW);
            int yc = min(max(yi, 0), HH - 1);
            int xc = min(max(xi, 0), WW - 1);
            sIdx[p][k][j] = (yc * WW + xc) * 4;           // byte offset
            float wy = (j >> 1) ? ly : 1.f - ly;
            float wx = (j & 1) ? lx : 1.f - lx;
            sWt[p][k][j] = valid ? wy * wx * mmv : 0.f;
        }
    }
    __syncthreads();

    const int p   = lane & 31;      // pixel within tile (gather role)
    const int ch2 = lane >> 5;      // channel half within wave's 16
    const int l3  = lane >> 3, l7 = lane & 7;   // B-staging roles
    const int n15 = lane & 15, q4 = lane >> 4;  // MFMA frag roles

    f32x4 acc[2][4];
    #pragma unroll
    for (int i = 0; i < 2; i++)
        #pragma unroll
        for (int j = 0; j < 4; j++)
            acc[i][j] = (f32x4){0.f, 0.f, 0.f, 0.f};

    for (int k = 0; k < 9; k++) {
        const int4   I  = *(const int4*)&sIdx[p][k][0];
        const float4 Wt = *(const float4*)&sWt[p][k][0];

        for (int cc = 0; cc < 4; cc++) {
            // --- stage B chunk: rows [wv*64, +64), K cols [k*256+cc*64, +64)
            #pragma unroll
            for (int j = 0; j < 8; j++) {
                const char* g = (const char*)wbfT
                    + ((size_t)(wv * 64 + j * 8 + l3) * 2304 + k * 256 + cc * 64) * 2
                    + l7 * 16;
                char* l = (char*)sB + wv * 8192 + j * 1024;
                __builtin_amdgcn_global_load_lds(
                    (const __attribute__((address_space(1))) void*)g,
                    (__attribute__((address_space(3))) void*)l, 16, 0, 0);
            }

            // --- gather 8 channels into sA row p ---
            const char* sbase = (const char*)x
                + ((size_t)(b * C1 + cc * 64 + wv * 16) << 14);
            bf16x8 v8;
            #pragma unroll
            for (int i = 0; i < 8; i++) {
                const char* cbi = sbase + ((size_t)(ch2 * 8 + i) << 14);
                float v = Wt.x * *(const float*)(cbi + I.x)
                        + Wt.y * *(const float*)(cbi + I.y)
                        + Wt.z * *(const float*)(cbi + I.z)
                        + Wt.w * *(const float*)(cbi + I.w);
                v8[i] = (__bf16)v;
            }
            *(bf16x8*)&sA[p * 72 + wv * 16 + ch2 * 8] = v8;
            __syncthreads();

            // --- MFMA on the 64-K chunk ---
            bf16x8 af[2][2];
            #pragma unroll
            for (int mf = 0; mf < 2; mf++)
                #pragma unroll
                for (int ks = 0; ks < 2; ks++)
                    af[mf][ks] = *(const bf16x8*)&sA[(mf * 16 + n15) * 72 + q4 * 8 + ks * 32];

            #pragma unroll
            for (int nf = 0; nf < 4; nf++) {
                #pragma unroll
                for (int ks = 0; ks < 2; ks++) {
                    bf16x8 bfr = *(const bf16x8*)&sB[(wv * 64 + nf * 16 + n15) * 64 + q4 * 8 + ks * 32];
                    #pragma unroll
                    for (int mf = 0; mf < 2; mf++)
                        acc[mf][nf] = __builtin_amdgcn_mfma_f32_16x16x32_bf16(
                            af[mf][ks], bfr, acc[mf][nf], 0, 0, 0);
                }
            }
            __syncthreads();
        }
    }

    // --- Epilogue: BN + SiLU; C/D layout col=lane&15 (o), row=q4*4+r (pixel)
    #pragma unroll
    for (int nf = 0; nf < 4; nf++) {
        int o = wv * 64 + nf * 16 + n15;
        float inv = gamma[o] * rsqrtf(rvar[o] + EPSV);
        float sh = beta[o] - rmean[o] * inv;
        #pragma unroll
        for (int mf = 0; mf < 2; mf++) {
            #pragma unroll
            for (int r = 0; r < 4; r++) {
                int m = mf * 16 + q4 * 4 + r;
                float y = acc[mf][nf][r] * inv + sh;
                out[(size_t)((b * C2 + o) << 12) + hwBase + m]
                    = y * (1.f / (1.f + __expf(-y)));
            }
        }
    }
}

// ---------------------------------------------------------------------------
extern "C" void kernel_launch(void* const* d_in, const int* in_sizes, int n_in,
                              void* d_out, int out_size, void* d_ws, size_t ws_size,
                              hipStream_t stream) {
    const float* x      = (const float*)d_in[0];
    const float* w_off  = (const float*)d_in[1];
    const float* b_off  = (const float*)d_in[2];
    const float* w_dcn  = (const float*)d_in[3];
    const float* gamma  = (const float*)d_in[4];
    const float* beta   = (const float*)d_in[5];
    const float* rmean  = (const float*)d_in[6];
    const float* rvar   = (const float*)d_in[7];
    float* out = (float*)d_out;

    char* ws = (char*)d_ws;
    float*  om       = (float*)(ws + OM_OFF);
    float*  partials = (float*)(ws + PART_OFF);
    __bf16* wbfT     = (__bf16*)(ws + WBF_OFF);

    wprep_kernel<<<2304, 256, 0, stream>>>(w_dcn, wbfT);
    offset_partial_kernel<<<512, 256, 0, stream>>>(x, w_off, partials);
    offset_reduce_kernel<<<864, 256, 0, stream>>>(partials, b_off, om);
    fused_kernel<<<256, 256, 0, stream>>>(x, om, wbfT, gamma, beta,
                                          rmean, rvar, out);
}